// Round 9
// baseline (212.422 us; speedup 1.0000x reference)
//
#include <hip/hip_runtime.h>
#include <hip/hip_bf16.h>
#include <cstdint>
#include <cstddef>

#define N_NODES 10000
#define T_STEPS 6
#define F_IN    64
#define HID     64
#define HEADS   4
#define E_EDGES 160000
#define EP      (E_EDGES + N_NODES)   /* 170000 edges incl self-loops */
#define TN      (T_STEPS * N_NODES)   /* 60000 */
#define NTILES  (TN / 16)             /* 3750 */
#define CAP     96                    /* fixed CSR bucket capacity */

typedef __hip_bfloat16 bf16;
typedef __attribute__((ext_vector_type(8))) short short8;
typedef __attribute__((ext_vector_type(4))) float floatx4;

__device__ __forceinline__ float bfu(unsigned short s) { return __uint_as_float((unsigned)s << 16); }
__device__ __forceinline__ unsigned short f2bu(float f) {
    bf16 b = __float2bfloat16(f);
    return *(unsigned short*)&b;
}
__device__ __forceinline__ void lds_fence() {
    asm volatile("s_waitcnt lgkmcnt(0)" ::: "memory");
}
/* bijective XCD-aware swizzle (verified r6: FETCH 57->12 MB): each XCD gets a
   contiguous chunk of tiles so its gather working set stays in its own L2. */
__device__ __forceinline__ int xcd_swizzle(int b, int nblk) {
    int q = nblk >> 3, r = nblk & 7;
    int x = b & 7, j = b >> 3;
    return (x < r ? x * (q + 1) : r * (q + 1) + (x - r) * q) + j;
}

/* ---------------- CSR build: direct fixed-stride buckets ---------------- */

__global__ void k_scatter(const int* ei, int* fill,
                          int* csr_src, int* csr_eid, float* out_ei) {
    int e = blockIdx.x * blockDim.x + threadIdx.x;
    if (e >= EP) return;
    int src = (e < E_EDGES) ? ei[e] : (e - E_EDGES);
    int dst = (e < E_EDGES) ? ei[E_EDGES + e] : (e - E_EDGES);
    int pos = atomicAdd(&fill[dst], 1);
    if (pos < CAP) {
        csr_src[dst * CAP + pos] = src;
        csr_eid[dst * CAP + pos] = e;
    }
    out_ei[e] = (float)src;
    out_ei[EP + e] = (float)dst;
}

/* ------- prep: weight bf16 preconversion + P-matrices ------- */

__global__ __launch_bounds__(256) void k_prep(const float* __restrict__ W0,
                                              const float* __restrict__ W1,
                                              const float* __restrict__ a_src0,
                                              const float* __restrict__ a_dst0,
                                              const float* __restrict__ a_src1,
                                              const float* __restrict__ a_dst1,
                                              const float* __restrict__ W_ih,
                                              const float* __restrict__ W_hh,
                                              bf16* __restrict__ W0bt,
                                              bf16* __restrict__ W1bt,
                                              bf16* __restrict__ wihb,
                                              bf16* __restrict__ whhb,
                                              float* __restrict__ P0s,
                                              float* __restrict__ P0d,
                                              float* __restrict__ P1s,
                                              float* __restrict__ P1d) {
    int b = blockIdx.x, tid = threadIdx.x;
    if (b == 176) {          /* P1: layer-1 logit projection */
        int h = tid >> 6, k = tid & 63;
        float ps = 0.f, pd = 0.f;
        for (int c = 0; c < 64; c++) {
            float wv = W1[k * 256 + h * 64 + c];
            ps += wv * a_src1[h * 64 + c];
            pd += wv * a_dst1[h * 64 + c];
        }
        P1s[h * 64 + k] = ps;
        P1d[h * 64 + k] = pd;
        return;
    }
    if (b == 177) {          /* P0: layer-0 logit projection */
        int h = tid >> 6, k = tid & 63;
        float ps = 0.f, pd = 0.f;
        for (int c = 0; c < 16; c++) {
            float wv = W0[k * 64 + h * 16 + c];
            ps += wv * a_src0[h * 16 + c];
            pd += wv * a_dst0[h * 16 + c];
        }
        P0s[h * 64 + k] = ps;
        P0d[h * 64 + k] = pd;
        return;
    }
    int i = b * 256 + tid;
    if (i < 4096) {
        /* W0 transposed [c][k] for gemm0 LDS */
        W0bt[i] = __float2bfloat16(W0[(i & 63) * 64 + (i >> 6)]);
    } else if (i < 20480) {
        /* W1 in [c][K] layout (c = out col, K = h*64+f contraction) */
        int j = i - 4096; int c = j >> 8, K = j & 255;
        W1bt[j] = __float2bfloat16(W1[(K & 63) * 256 + (K >> 6) * 64 + c]);
    } else if (i < 32768) {
        wihb[i - 20480] = __float2bfloat16(W_ih[i - 20480]);
    } else {
        whhb[i - 32768] = __float2bfloat16(W_hh[i - 32768]);
    }
}

/* ---------------- GAT layer 0 GEMM (MFMA) + logits via P0 ---------------- */
__global__ __launch_bounds__(256) void k_gemm0(const float* __restrict__ x,
                                               const bf16* __restrict__ W0bt,
                                               const float* __restrict__ P0s,
                                               const float* __restrict__ P0d,
                                               bf16* __restrict__ XW0b,
                                               float* __restrict__ ALS0,
                                               float* __restrict__ ALD0) {
    __shared__ __align__(16) bf16 wt[64 * 64];   /* [c][k], 8 KB */
    int tid = threadIdx.x;
    for (int i = tid; i < 512; i += 256)
        ((short8*)wt)[i] = ((const short8*)W0bt)[i];
    __syncthreads();
    int wv = tid >> 6, lane = tid & 63;
    int tile = blockIdx.x * 4 + wv;
    if (tile >= NTILES) return;
    int rb = tile * 16;
    int m = lane & 15, quad = lane >> 4;
    int row = rb + m;
    int t = row / N_NODES, n = row - t * N_NODES;
    const float* xr = x + ((size_t)n * T_STEPS + t) * F_IN + quad * 8;
    short8 a0, a1;
#pragma unroll
    for (int j = 0; j < 8; j++) {
        a0[j] = (short)f2bu(xr[j]);
        a1[j] = (short)f2bu(xr[32 + j]);
    }
    floatx4 acc[4];
#pragma unroll
    for (int ct = 0; ct < 4; ct++) {
        short8 bb0 = *(const short8*)(wt + (ct * 16 + m) * 64 + quad * 8);
        short8 bb1 = *(const short8*)(wt + (ct * 16 + m) * 64 + 32 + quad * 8);
        floatx4 a = {0.f, 0.f, 0.f, 0.f};
        a = __builtin_amdgcn_mfma_f32_16x16x32_bf16(a0, bb0, a, 0, 0, 0);
        a = __builtin_amdgcn_mfma_f32_16x16x32_bf16(a1, bb1, a, 0, 0, 0);
        acc[ct] = a;
    }
    /* logit tile: cols 0..3 = P0s rows, 4..7 = P0d rows */
    short8 p0, p1;
#pragma unroll
    for (int j = 0; j < 8; j++) {
        int k0 = quad * 8 + j, k1 = 32 + quad * 8 + j;
        float v0 = 0.f, v1 = 0.f;
        if (m < 4)      { v0 = P0s[m * 64 + k0];       v1 = P0s[m * 64 + k1]; }
        else if (m < 8) { v0 = P0d[(m - 4) * 64 + k0]; v1 = P0d[(m - 4) * 64 + k1]; }
        p0[j] = (short)f2bu(v0);
        p1[j] = (short)f2bu(v1);
    }
    floatx4 ac5 = {0.f, 0.f, 0.f, 0.f};
    ac5 = __builtin_amdgcn_mfma_f32_16x16x32_bf16(a0, p0, ac5, 0, 0, 0);
    ac5 = __builtin_amdgcn_mfma_f32_16x16x32_bf16(a1, p1, ac5, 0, 0, 0);
#pragma unroll
    for (int ct = 0; ct < 4; ct++)
#pragma unroll
        for (int r = 0; r < 4; r++)
            XW0b[(size_t)(rb + quad * 4 + r) * 64 + ct * 16 + m] = __float2bfloat16(acc[ct][r]);
#pragma unroll
    for (int r = 0; r < 4; r++) {
        int orow = rb + quad * 4 + r;
        if (m < 4)      ALS0[orow * 4 + m] = ac5[r];
        else if (m < 8) ALD0[orow * 4 + (m - 4)] = ac5[r];
    }
}

/* -------- fused layer-0: SINGLE-PASS softmax+agg + layer-1 logits --------
   Lane il covers H0 features il*4..il*4+3 (all in head il>>2). Per edge:
   one head-logit scalar load (broadcast line), ONE exp, unnormalized FMA;
   sum is lane-redundant (no reduction). srcs in [CAP][16] layout: read
   bank = g + 16*(k&1) -> conflict-free for any per-group k mix. */
__global__ __launch_bounds__(256) void k_fused0(const int* __restrict__ fill,
                                                const int* __restrict__ csr_src,
                                                const bf16* __restrict__ XW0b,
                                                const float* __restrict__ ALS0,
                                                const float* __restrict__ ALD0,
                                                const float* __restrict__ b0,
                                                const float* __restrict__ P1s,
                                                const float* __restrict__ P1d,
                                                bf16* __restrict__ H0b,
                                                float* __restrict__ ALS1,
                                                float* __restrict__ ALD1) {
    __shared__ int srcs[CAP][16];   /* 6 KB, conflict-free reads */
    int tid = threadIdx.x;
    int wv = tid >> 6, lane = tid & 63;
    int sub = lane >> 4, il = lane & 15;
    int g = wv * 4 + sub;
    int tile = xcd_swizzle(blockIdx.x, NTILES);
    int wid = tile * 16 + g;
    int t = wid / N_NODES, n = wid - t * N_NODES;
    int deg = min(fill[n], CAP);
    int rs = n * CAP;
    int tb = t * N_NODES;
    int hsel = il >> 2;
    float adh = ALD0[(size_t)wid * 4 + hsel];
    for (int idx = il; idx < deg; idx += 16)
        srcs[idx][g] = csr_src[rs + idx];
    lds_fence();
    float ssum = 0.f, a0 = 0.f, a1 = 0.f, a2 = 0.f, a3 = 0.f;
    const bf16* hrow = XW0b + (size_t)tb * 64 + il * 4;
    const float* alsb = ALS0 + (size_t)tb * 4 + hsel;
    for (int k = 0; k < deg; k++) {
        int sx = srcs[k][g];
        float l = alsb[(size_t)sx * 4] + adh;
        l = l > 0.f ? l : 0.2f * l;
        float e = __expf(fminf(l, 80.f));
        ssum += e;
        ushort4 u = *(const ushort4*)(hrow + (size_t)sx * 64);
        a0 += e * bfu(u.x); a1 += e * bfu(u.y);
        a2 += e * bfu(u.z); a3 += e * bfu(u.w);
    }
    float iv = 1.f / (ssum + 1e-16f);
    float4 bv = *(const float4*)(b0 + il * 4);
    float v0 = a0 * iv + bv.x; v0 = v0 > 0.f ? v0 : (__expf(v0) - 1.f);
    float v1 = a1 * iv + bv.y; v1 = v1 > 0.f ? v1 : (__expf(v1) - 1.f);
    float v2 = a2 * iv + bv.z; v2 = v2 > 0.f ? v2 : (__expf(v2) - 1.f);
    float v3 = a3 * iv + bv.w; v3 = v3 > 0.f ? v3 : (__expf(v3) - 1.f);
    ushort4 o4;
    o4.x = f2bu(v0); o4.y = f2bu(v1); o4.z = f2bu(v2); o4.w = f2bu(v3);
    *(ushort4*)(H0b + (size_t)wid * 64 + il * 4) = o4;

    /* ---- fused layer-1 logits: ALS1/ALD1 from the f32 H0 registers ---- */
    float ps[4], pd[4];
#pragma unroll
    for (int h = 0; h < 4; h++) {
        float4 s4 = *(const float4*)(P1s + h * 64 + il * 4);
        float4 d4 = *(const float4*)(P1d + h * 64 + il * 4);
        ps[h] = v0 * s4.x + v1 * s4.y + v2 * s4.z + v3 * s4.w;
        pd[h] = v0 * d4.x + v1 * d4.y + v2 * d4.z + v3 * d4.w;
    }
#pragma unroll
    for (int o = 1; o <= 8; o <<= 1) {
#pragma unroll
        for (int h = 0; h < 4; h++) {
            ps[h] += __shfl_xor(ps[h], o, 64);
            pd[h] += __shfl_xor(pd[h], o, 64);
        }
    }
    if (il == 0) {
        float4 w1; w1.x = ps[0]; w1.y = ps[1]; w1.z = ps[2]; w1.w = ps[3];
        *(float4*)(ALS1 + (size_t)wid * 4) = w1;
        float4 w2; w2.x = pd[0]; w2.y = pd[1]; w2.z = pd[2]; w2.w = pd[3];
        *(float4*)(ALD1 + (size_t)wid * 4) = w2;
    }
}

/* -------- fused layer-1: SINGLE-PASS 4-exp softmax+agg + GEMM + LN ------
   Lane il owns features il*4..il*4+3 and accumulates acc[4][4] (all 4
   heads x its 4 features). Per edge: broadcast float4 ALS1 load, 4 exps
   (head sums lane-redundant, no reductions), one distinct ushort4 gather
   (16 lanes cover the 128B row exactly once). alpha (t=5) needs no
   shuffles. Phase 2: LDS-staged 16x256 -> 16x64x256 MFMA -> LN. */
__global__ __launch_bounds__(256) void k_fused1(const int* __restrict__ fill,
                                                const int* __restrict__ csr_src,
                                                const int* __restrict__ csr_eid,
                                                const bf16* __restrict__ H0b,
                                                const float* __restrict__ ALS1,
                                                const float* __restrict__ ALD1,
                                                const bf16* __restrict__ W1bt,
                                                const float* __restrict__ b1,
                                                const float* __restrict__ ln_g,
                                                const float* __restrict__ ln_b,
                                                bf16* __restrict__ HSb,
                                                float* __restrict__ out_alpha) {
    __shared__ __align__(16) union SM {
        int srcs[CAP][16];                                   /* 6 KB, conflict-free */
        struct { bf16 ast[16][264]; float ost[16][68]; } q;  /* 12.8 KB */
    } sm;
    int tid = threadIdx.x;
    int wv = tid >> 6, lane = tid & 63;
    int sub = lane >> 4, il = lane & 15;
    int g = wv * 4 + sub;
    int tile = xcd_swizzle(blockIdx.x, NTILES);
    int wid = tile * 16 + g;
    int t = wid / N_NODES, n = wid - t * N_NODES;
    int deg = min(fill[n], CAP);
    int rs = n * CAP;
    int tb = t * N_NODES;
    bool do_out = (t == T_STEPS - 1);
    float4 ad4 = *(const float4*)(ALD1 + (size_t)wid * 4);
    for (int idx = il; idx < deg; idx += 16)
        sm.srcs[idx][g] = csr_src[rs + idx];
    lds_fence();
    float s0 = 0.f, s1 = 0.f, s2 = 0.f, s3 = 0.f;
    float acc[4][4];
#pragma unroll
    for (int h = 0; h < 4; h++)
#pragma unroll
        for (int j = 0; j < 4; j++) acc[h][j] = 0.f;
    const bf16* hrow = H0b + (size_t)tb * 64 + il * 4;
    const float* alsb = ALS1 + (size_t)tb * 4;
    for (int k = 0; k < deg; k++) {
        int sx = sm.srcs[k][g];
        float4 as = *(const float4*)(alsb + (size_t)sx * 4);   /* broadcast */
        float l0 = as.x + ad4.x; l0 = l0 > 0.f ? l0 : 0.2f * l0;
        float l1 = as.y + ad4.y; l1 = l1 > 0.f ? l1 : 0.2f * l1;
        float l2 = as.z + ad4.z; l2 = l2 > 0.f ? l2 : 0.2f * l2;
        float l3 = as.w + ad4.w; l3 = l3 > 0.f ? l3 : 0.2f * l3;
        float e0 = __expf(fminf(l0, 80.f));
        float e1 = __expf(fminf(l1, 80.f));
        float e2 = __expf(fminf(l2, 80.f));
        float e3 = __expf(fminf(l3, 80.f));
        s0 += e0; s1 += e1; s2 += e2; s3 += e3;
        ushort4 u = *(const ushort4*)(hrow + (size_t)sx * 64); /* distinct 8B */
        float x0 = bfu(u.x), x1 = bfu(u.y), x2 = bfu(u.z), x3 = bfu(u.w);
        acc[0][0] += e0 * x0; acc[0][1] += e0 * x1; acc[0][2] += e0 * x2; acc[0][3] += e0 * x3;
        acc[1][0] += e1 * x0; acc[1][1] += e1 * x1; acc[1][2] += e1 * x2; acc[1][3] += e1 * x3;
        acc[2][0] += e2 * x0; acc[2][1] += e2 * x1; acc[2][2] += e2 * x2; acc[2][3] += e2 * x3;
        acc[3][0] += e3 * x0; acc[3][1] += e3 * x1; acc[3][2] += e3 * x2; acc[3][3] += e3 * x3;
    }
    float iv0 = 1.f / (s0 + 1e-16f), iv1 = 1.f / (s1 + 1e-16f);
    float iv2 = 1.f / (s2 + 1e-16f), iv3 = 1.f / (s3 + 1e-16f);

    if (do_out) {
        for (int idx = il; idx < deg; idx += 16) {
            int sx = sm.srcs[idx][g];
            float4 as = *(const float4*)(alsb + (size_t)sx * 4);
            float l0 = as.x + ad4.x; l0 = l0 > 0.f ? l0 : 0.2f * l0;
            float l1 = as.y + ad4.y; l1 = l1 > 0.f ? l1 : 0.2f * l1;
            float l2 = as.z + ad4.z; l2 = l2 > 0.f ? l2 : 0.2f * l2;
            float l3 = as.w + ad4.w; l3 = l3 > 0.f ? l3 : 0.2f * l3;
            float4 o4;
            o4.x = __expf(fminf(l0, 80.f)) * iv0;
            o4.y = __expf(fminf(l1, 80.f)) * iv1;
            o4.z = __expf(fminf(l2, 80.f)) * iv2;
            o4.w = __expf(fminf(l3, 80.f)) * iv3;
            int eid = csr_eid[rs + idx];
            *(float4*)(out_alpha + (size_t)eid * 4) = o4;
        }
    }

    /* ---- phase 2: stage agg (bf16) -> 16x64x256 MFMA -> LN -> HSb ---- */
    __syncthreads();                       /* all srcs reads complete */
    float ivh[4] = { iv0, iv1, iv2, iv3 };
#pragma unroll
    for (int h = 0; h < 4; h++) {
        ushort4 o4;
        o4.x = f2bu(acc[h][0] * ivh[h]);
        o4.y = f2bu(acc[h][1] * ivh[h]);
        o4.z = f2bu(acc[h][2] * ivh[h]);
        o4.w = f2bu(acc[h][3] * ivh[h]);
        *(ushort4*)&sm.q.ast[g][h * 64 + il * 4] = o4;   /* K = h*64 + feature */
    }
    __syncthreads();
    /* wave wv computes output columns [wv*16, wv*16+16) */
    int m = il, quad = sub;
    floatx4 ga = {0.f, 0.f, 0.f, 0.f};
    const bf16* wrow = W1bt + (size_t)(wv * 16 + m) * 256 + quad * 8;
#pragma unroll
    for (int kb = 0; kb < 8; kb++) {
        short8 afk = *(const short8*)&sm.q.ast[m][kb * 32 + quad * 8];
        short8 bfk = *(const short8*)(wrow + kb * 32);
        ga = __builtin_amdgcn_mfma_f32_16x16x32_bf16(afk, bfk, ga, 0, 0, 0);
    }
#pragma unroll
    for (int r = 0; r < 4; r++)
        sm.q.ost[quad * 4 + r][wv * 16 + m] = ga[r];
    __syncthreads();
    /* LN: wave wv handles rows wv*4+quad; 16 lanes (m) cover 64 cols */
    int row = wv * 4 + quad;
    float4 vv = *(const float4*)&sm.q.ost[row][m * 4];
    float4 bb = *(const float4*)(b1 + m * 4);
    float v0 = vv.x * 0.25f + bb.x; v0 = v0 > 0.f ? v0 : (__expf(v0) - 1.f);
    float v1 = vv.y * 0.25f + bb.y; v1 = v1 > 0.f ? v1 : (__expf(v1) - 1.f);
    float v2 = vv.z * 0.25f + bb.z; v2 = v2 > 0.f ? v2 : (__expf(v2) - 1.f);
    float v3 = vv.w * 0.25f + bb.w; v3 = v3 > 0.f ? v3 : (__expf(v3) - 1.f);
    float sv = v0 + v1 + v2 + v3;
#pragma unroll
    for (int o = 1; o <= 8; o <<= 1) sv += __shfl_xor(sv, o, 64);
    float mu = sv * (1.f / 64.f);
    float d0 = v0 - mu, d1 = v1 - mu, d2 = v2 - mu, d3 = v3 - mu;
    float qv = d0 * d0 + d1 * d1 + d2 * d2 + d3 * d3;
#pragma unroll
    for (int o = 1; o <= 8; o <<= 1) qv += __shfl_xor(qv, o, 64);
    float rinv = rsqrtf(qv * (1.f / 64.f) + 1e-5f);
    float4 gg = *(const float4*)(ln_g + m * 4);
    float4 lb = *(const float4*)(ln_b + m * 4);
    ushort4 ho;
    ho.x = f2bu(d0 * rinv * gg.x + lb.x);
    ho.y = f2bu(d1 * rinv * gg.y + lb.y);
    ho.z = f2bu(d2 * rinv * gg.z + lb.z);
    ho.w = f2bu(d3 * rinv * gg.w + lb.w);
    *(ushort4*)(HSb + (size_t)(tile * 16 + row) * 64 + m * 4) = ho;
}

/* ---------------- GRU: 625 blocks, 4 waves split the 192 gate rows -------
   One block per 16-node tile; wave wv owns h-features [wv*16, wv*16+16).
   B-fragments (bf16 W_ih/W_hh rows) live in registers across all 6 steps;
   h is exchanged via a padded LDS tile with 2 barriers/step. h0 = 0. */
__global__ __launch_bounds__(256) void k_gru(const bf16* __restrict__ HSb,
                                             const bf16* __restrict__ wihb,
                                             const float* __restrict__ b_ih,
                                             const bf16* __restrict__ whhb,
                                             const float* __restrict__ b_hh,
                                             float* __restrict__ outh) {
    __shared__ __align__(16) bf16 hbuf[16 * 72];   /* 2.25 KB, stride-72 pad */
    int tid = threadIdx.x;
    int wv = tid >> 6, lane = tid & 63;
    int rb = blockIdx.x * 16;
    int m = lane & 15, quad = lane >> 4;
    int fb = wv * 16;
    const int rowR = (fb + m) * 64, rowZ = (64 + fb + m) * 64, rowG = (128 + fb + m) * 64;
    short8 Br0 = *(const short8*)(wihb + rowR + quad * 8);
    short8 Br1 = *(const short8*)(wihb + rowR + 32 + quad * 8);
    short8 Bz0 = *(const short8*)(wihb + rowZ + quad * 8);
    short8 Bz1 = *(const short8*)(wihb + rowZ + 32 + quad * 8);
    short8 Bg0 = *(const short8*)(wihb + rowG + quad * 8);
    short8 Bg1 = *(const short8*)(wihb + rowG + 32 + quad * 8);
    short8 Cr0 = *(const short8*)(whhb + rowR + quad * 8);
    short8 Cr1 = *(const short8*)(whhb + rowR + 32 + quad * 8);
    short8 Cz0 = *(const short8*)(whhb + rowZ + quad * 8);
    short8 Cz1 = *(const short8*)(whhb + rowZ + 32 + quad * 8);
    short8 Cg0 = *(const short8*)(whhb + rowG + quad * 8);
    short8 Cg1 = *(const short8*)(whhb + rowG + 32 + quad * 8);
    float biR = b_ih[fb + m], biZ = b_ih[64 + fb + m], biG = b_ih[128 + fb + m];
    float bhR = b_hh[fb + m], bhZ = b_hh[64 + fb + m], bhG = b_hh[128 + fb + m];
    float hprev[4] = {0.f, 0.f, 0.f, 0.f};

    for (int t = 0; t < T_STEPS; t++) {
        const bf16* xr = HSb + ((size_t)t * N_NODES + rb + m) * 64;
        short8 ax0 = *(const short8*)(xr + quad * 8);
        short8 ax1 = *(const short8*)(xr + 32 + quad * 8);
        short8 ah0, ah1;
        if (t > 0) {
            ah0 = *(const short8*)(hbuf + m * 72 + quad * 8);
            ah1 = *(const short8*)(hbuf + m * 72 + 32 + quad * 8);
        }
        __syncthreads();   /* all reads of old h done before anyone writes new h */
        floatx4 aR = {0.f, 0.f, 0.f, 0.f}, aZ = {0.f, 0.f, 0.f, 0.f};
        floatx4 aGi = {0.f, 0.f, 0.f, 0.f}, aGh = {0.f, 0.f, 0.f, 0.f};
        aR = __builtin_amdgcn_mfma_f32_16x16x32_bf16(ax0, Br0, aR, 0, 0, 0);
        aR = __builtin_amdgcn_mfma_f32_16x16x32_bf16(ax1, Br1, aR, 0, 0, 0);
        aZ = __builtin_amdgcn_mfma_f32_16x16x32_bf16(ax0, Bz0, aZ, 0, 0, 0);
        aZ = __builtin_amdgcn_mfma_f32_16x16x32_bf16(ax1, Bz1, aZ, 0, 0, 0);
        aGi = __builtin_amdgcn_mfma_f32_16x16x32_bf16(ax0, Bg0, aGi, 0, 0, 0);
        aGi = __builtin_amdgcn_mfma_f32_16x16x32_bf16(ax1, Bg1, aGi, 0, 0, 0);
        if (t > 0) {
            aR = __builtin_amdgcn_mfma_f32_16x16x32_bf16(ah0, Cr0, aR, 0, 0, 0);
            aR = __builtin_amdgcn_mfma_f32_16x16x32_bf16(ah1, Cr1, aR, 0, 0, 0);
            aZ = __builtin_amdgcn_mfma_f32_16x16x32_bf16(ah0, Cz0, aZ, 0, 0, 0);
            aZ = __builtin_amdgcn_mfma_f32_16x16x32_bf16(ah1, Cz1, aZ, 0, 0, 0);
            aGh = __builtin_amdgcn_mfma_f32_16x16x32_bf16(ah0, Cg0, aGh, 0, 0, 0);
            aGh = __builtin_amdgcn_mfma_f32_16x16x32_bf16(ah1, Cg1, aGh, 0, 0, 0);
        }
#pragma unroll
        for (int r = 0; r < 4; r++) {
            float rr = 1.f / (1.f + __expf(-(aR[r] + biR + bhR)));
            float z  = 1.f / (1.f + __expf(-(aZ[r] + biZ + bhZ)));
            float g  = tanhf(aGi[r] + biG + rr * (aGh[r] + bhG));
            hprev[r] = (1.f - z) * g + z * hprev[r];
        }
        if (t < T_STEPS - 1) {
#pragma unroll
            for (int r = 0; r < 4; r++)
                hbuf[(quad * 4 + r) * 72 + fb + m] = __float2bfloat16(hprev[r]);
            __syncthreads();   /* writes visible before next step's reads */
        }
    }
#pragma unroll
    for (int r = 0; r < 4; r++)
        outh[(size_t)(rb + quad * 4 + r) * 64 + fb + m] = hprev[r];
}

/* ---------------- launch ---------------- */

extern "C" void kernel_launch(void* const* d_in, const int* in_sizes, int n_in,
                              void* d_out, int out_size, void* d_ws, size_t ws_size,
                              hipStream_t stream) {
    const float* x      = (const float*)d_in[0];
    const int*   ei     = (const int*)d_in[1];
    const float* W0     = (const float*)d_in[2];
    const float* a_src0 = (const float*)d_in[3];
    const float* a_dst0 = (const float*)d_in[4];
    const float* b0     = (const float*)d_in[5];
    const float* W1     = (const float*)d_in[6];
    const float* a_src1 = (const float*)d_in[7];
    const float* a_dst1 = (const float*)d_in[8];
    const float* b1     = (const float*)d_in[9];
    const float* ln_g   = (const float*)d_in[10];
    const float* ln_b   = (const float*)d_in[11];
    const float* W_ih   = (const float*)d_in[12];
    const float* W_hh   = (const float*)d_in[13];
    const float* b_ih   = (const float*)d_in[14];
    const float* b_hh   = (const float*)d_in[15];
    float* out = (float*)d_out;

    char* w = (char*)d_ws;
    size_t off = 0;
    auto take = [&](size_t bytes) -> void* {
        void* p = w + off;
        off = (off + bytes + 255) & ~(size_t)255;
        return p;
    };
    int*   fill    = (int*)take(N_NODES * 4);
    int*   csr_src = (int*)take((size_t)N_NODES * CAP * 4);
    int*   csr_eid = (int*)take((size_t)N_NODES * CAP * 4);
    bf16*  XW0b    = (bf16*)take((size_t)TN * 64 * 2);
    float* ALS0    = (float*)take((size_t)TN * 4 * 4);
    float* ALD0    = (float*)take((size_t)TN * 4 * 4);
    bf16*  H0b     = (bf16*)take((size_t)TN * 64 * 2);
    float* P0s     = (float*)take(256 * 4);
    float* P0d     = (float*)take(256 * 4);
    float* P1s     = (float*)take(256 * 4);
    float* P1d     = (float*)take(256 * 4);
    float* ALS1    = (float*)take((size_t)TN * 4 * 4);
    float* ALD1    = (float*)take((size_t)TN * 4 * 4);
    bf16*  HSb     = (bf16*)take((size_t)TN * 64 * 2);
    bf16*  W0bt    = (bf16*)take(4096 * 2);
    bf16*  W1bt    = (bf16*)take(16384 * 2);
    bf16*  wihb    = (bf16*)take(12288 * 2);
    bf16*  whhb    = (bf16*)take(12288 * 2);
    (void)ws_size; (void)in_sizes; (void)n_in; (void)out_size;

    const int B = 256;
    float* out_ei = out + (size_t)N_NODES * HID + (size_t)EP * HEADS;

    /* CSR build (direct fixed-stride buckets) + prep */
    hipMemsetAsync(fill, 0, N_NODES * 4, stream);
    k_prep<<<178, B, 0, stream>>>(W0, W1, a_src0, a_dst0, a_src1, a_dst1, W_ih, W_hh,
                                  W0bt, W1bt, wihb, whhb, P0s, P0d, P1s, P1d);
    k_scatter<<<(EP + B - 1) / B, B, 0, stream>>>(ei, fill, csr_src, csr_eid, out_ei);

    const int GT = (NTILES + 3) / 4;   /* 938 blocks for 16-row-tile MFMA kernels */
    /* GAT layer 0 (+ layer-1 logits fused into the epilogue) */
    k_gemm0<<<GT, B, 0, stream>>>(x, W0bt, P0s, P0d, XW0b, ALS0, ALD0);
    k_fused0<<<NTILES, B, 0, stream>>>(fill, csr_src, XW0b, ALS0, ALD0, b0,
                                       P1s, P1d, H0b, ALS1, ALD1);

    /* GAT layer 1 (+ epilogue GEMM + LN fused) */
    k_fused1<<<NTILES, B, 0, stream>>>(fill, csr_src, csr_eid, H0b, ALS1, ALD1,
                                       W1bt, b1, ln_g, ln_b, HSb,
                                       out + (size_t)N_NODES * HID);

    /* GRU: all 6 steps, 625 blocks × 4 gate-split waves, writes hT to out */
    k_gru<<<N_NODES / 16, B, 0, stream>>>(HSb, wihb, b_ih, whhb, b_hh, out);
}

// Round 10
// 201.438 us; speedup vs baseline: 1.0545x; 1.0545x over previous
//
#include <hip/hip_runtime.h>
#include <hip/hip_bf16.h>
#include <cstdint>
#include <cstddef>

#define N_NODES 10000
#define T_STEPS 6
#define F_IN    64
#define HID     64
#define HEADS   4
#define E_EDGES 160000
#define EP      (E_EDGES + N_NODES)   /* 170000 edges incl self-loops */
#define TN      (T_STEPS * N_NODES)   /* 60000 */
#define NTILES  (TN / 16)             /* 3750 */
#define CAP     96                    /* fixed CSR bucket capacity */

typedef __hip_bfloat16 bf16;
typedef __attribute__((ext_vector_type(8))) short short8;
typedef __attribute__((ext_vector_type(4))) float floatx4;

__device__ __forceinline__ float bfu(unsigned short s) { return __uint_as_float((unsigned)s << 16); }
__device__ __forceinline__ unsigned short f2bu(float f) {
    bf16 b = __float2bfloat16(f);
    return *(unsigned short*)&b;
}
__device__ __forceinline__ void lds_fence() {
    asm volatile("s_waitcnt lgkmcnt(0)" ::: "memory");
}
/* bijective XCD-aware swizzle (verified r6: FETCH 57->12 MB): each XCD gets a
   contiguous chunk of tiles so its gather working set stays in its own L2. */
__device__ __forceinline__ int xcd_swizzle(int b, int nblk) {
    int q = nblk >> 3, r = nblk & 7;
    int x = b & 7, j = b >> 3;
    return (x < r ? x * (q + 1) : r * (q + 1) + (x - r) * q) + j;
}

/* ---------------- CSR build: direct fixed-stride buckets ---------------- */

__global__ void k_scatter(const int* ei, int* fill,
                          int* csr_src, int* csr_eid, float* out_ei) {
    int e = blockIdx.x * blockDim.x + threadIdx.x;
    if (e >= EP) return;
    int src = (e < E_EDGES) ? ei[e] : (e - E_EDGES);
    int dst = (e < E_EDGES) ? ei[E_EDGES + e] : (e - E_EDGES);
    int pos = atomicAdd(&fill[dst], 1);
    if (pos < CAP) {
        csr_src[dst * CAP + pos] = src;
        csr_eid[dst * CAP + pos] = e;
    }
    out_ei[e] = (float)src;
    out_ei[EP + e] = (float)dst;
}

/* ------- prep: weight bf16 preconversion + P-matrices ------- */

__global__ __launch_bounds__(256) void k_prep(const float* __restrict__ W0,
                                              const float* __restrict__ W1,
                                              const float* __restrict__ a_src0,
                                              const float* __restrict__ a_dst0,
                                              const float* __restrict__ a_src1,
                                              const float* __restrict__ a_dst1,
                                              const float* __restrict__ W_ih,
                                              const float* __restrict__ W_hh,
                                              bf16* __restrict__ W0bt,
                                              bf16* __restrict__ W1bt,
                                              bf16* __restrict__ wihb,
                                              bf16* __restrict__ whhb,
                                              float* __restrict__ P0s,
                                              float* __restrict__ P0d,
                                              float* __restrict__ P1s,
                                              float* __restrict__ P1d) {
    int b = blockIdx.x, tid = threadIdx.x;
    if (b == 176) {          /* P1: layer-1 logit projection */
        int h = tid >> 6, k = tid & 63;
        float ps = 0.f, pd = 0.f;
        for (int c = 0; c < 64; c++) {
            float wv = W1[k * 256 + h * 64 + c];
            ps += wv * a_src1[h * 64 + c];
            pd += wv * a_dst1[h * 64 + c];
        }
        P1s[h * 64 + k] = ps;
        P1d[h * 64 + k] = pd;
        return;
    }
    if (b == 177) {          /* P0: layer-0 logit projection */
        int h = tid >> 6, k = tid & 63;
        float ps = 0.f, pd = 0.f;
        for (int c = 0; c < 16; c++) {
            float wv = W0[k * 64 + h * 16 + c];
            ps += wv * a_src0[h * 16 + c];
            pd += wv * a_dst0[h * 16 + c];
        }
        P0s[h * 64 + k] = ps;
        P0d[h * 64 + k] = pd;
        return;
    }
    int i = b * 256 + tid;
    if (i < 4096) {
        /* W0 transposed [c][k] for gemm0 LDS */
        W0bt[i] = __float2bfloat16(W0[(i & 63) * 64 + (i >> 6)]);
    } else if (i < 20480) {
        /* W1 in [c][K] layout (c = out col, K = h*64+f contraction) */
        int j = i - 4096; int c = j >> 8, K = j & 255;
        W1bt[j] = __float2bfloat16(W1[(K & 63) * 256 + (K >> 6) * 64 + c]);
    } else if (i < 32768) {
        wihb[i - 20480] = __float2bfloat16(W_ih[i - 20480]);
    } else {
        whhb[i - 32768] = __float2bfloat16(W_hh[i - 32768]);
    }
}

/* ---------------- GAT layer 0 GEMM (MFMA) + logits via P0 ---------------- */
__global__ __launch_bounds__(256) void k_gemm0(const float* __restrict__ x,
                                               const bf16* __restrict__ W0bt,
                                               const float* __restrict__ P0s,
                                               const float* __restrict__ P0d,
                                               bf16* __restrict__ XW0b,
                                               float* __restrict__ ALS0,
                                               float* __restrict__ ALD0) {
    __shared__ __align__(16) bf16 wt[64 * 64];   /* [c][k], 8 KB */
    int tid = threadIdx.x;
    for (int i = tid; i < 512; i += 256)
        ((short8*)wt)[i] = ((const short8*)W0bt)[i];
    __syncthreads();
    int wv = tid >> 6, lane = tid & 63;
    int tile = blockIdx.x * 4 + wv;
    if (tile >= NTILES) return;
    int rb = tile * 16;
    int m = lane & 15, quad = lane >> 4;
    int row = rb + m;
    int t = row / N_NODES, n = row - t * N_NODES;
    const float* xr = x + ((size_t)n * T_STEPS + t) * F_IN + quad * 8;
    short8 a0, a1;
#pragma unroll
    for (int j = 0; j < 8; j++) {
        a0[j] = (short)f2bu(xr[j]);
        a1[j] = (short)f2bu(xr[32 + j]);
    }
    floatx4 acc[4];
#pragma unroll
    for (int ct = 0; ct < 4; ct++) {
        short8 bb0 = *(const short8*)(wt + (ct * 16 + m) * 64 + quad * 8);
        short8 bb1 = *(const short8*)(wt + (ct * 16 + m) * 64 + 32 + quad * 8);
        floatx4 a = {0.f, 0.f, 0.f, 0.f};
        a = __builtin_amdgcn_mfma_f32_16x16x32_bf16(a0, bb0, a, 0, 0, 0);
        a = __builtin_amdgcn_mfma_f32_16x16x32_bf16(a1, bb1, a, 0, 0, 0);
        acc[ct] = a;
    }
    /* logit tile: cols 0..3 = P0s rows, 4..7 = P0d rows */
    short8 p0, p1;
#pragma unroll
    for (int j = 0; j < 8; j++) {
        int k0 = quad * 8 + j, k1 = 32 + quad * 8 + j;
        float v0 = 0.f, v1 = 0.f;
        if (m < 4)      { v0 = P0s[m * 64 + k0];       v1 = P0s[m * 64 + k1]; }
        else if (m < 8) { v0 = P0d[(m - 4) * 64 + k0]; v1 = P0d[(m - 4) * 64 + k1]; }
        p0[j] = (short)f2bu(v0);
        p1[j] = (short)f2bu(v1);
    }
    floatx4 ac5 = {0.f, 0.f, 0.f, 0.f};
    ac5 = __builtin_amdgcn_mfma_f32_16x16x32_bf16(a0, p0, ac5, 0, 0, 0);
    ac5 = __builtin_amdgcn_mfma_f32_16x16x32_bf16(a1, p1, ac5, 0, 0, 0);
#pragma unroll
    for (int ct = 0; ct < 4; ct++)
#pragma unroll
        for (int r = 0; r < 4; r++)
            XW0b[(size_t)(rb + quad * 4 + r) * 64 + ct * 16 + m] = __float2bfloat16(acc[ct][r]);
#pragma unroll
    for (int r = 0; r < 4; r++) {
        int orow = rb + quad * 4 + r;
        if (m < 4)      ALS0[orow * 4 + m] = ac5[r];
        else if (m < 8) ALD0[orow * 4 + (m - 4)] = ac5[r];
    }
}

/* -------- fused layer-0: SINGLE-PASS softmax+agg + layer-1 logits --------
   Lane il covers H0 features il*4..il*4+3 (all in head il>>2). Per edge:
   one head-logit scalar load (broadcast line), ONE exp, unnormalized FMA;
   sum is lane-redundant (no reduction). No cross-lane exp redundancy
   because layer-0 lanes are head-aligned (concat output layout). */
__global__ __launch_bounds__(256) void k_fused0(const int* __restrict__ fill,
                                                const int* __restrict__ csr_src,
                                                const bf16* __restrict__ XW0b,
                                                const float* __restrict__ ALS0,
                                                const float* __restrict__ ALD0,
                                                const float* __restrict__ b0,
                                                const float* __restrict__ P1s,
                                                const float* __restrict__ P1d,
                                                bf16* __restrict__ H0b,
                                                float* __restrict__ ALS1,
                                                float* __restrict__ ALD1) {
    __shared__ int srcs[CAP][16];   /* 6 KB, conflict-free reads */
    int tid = threadIdx.x;
    int wv = tid >> 6, lane = tid & 63;
    int sub = lane >> 4, il = lane & 15;
    int g = wv * 4 + sub;
    int tile = xcd_swizzle(blockIdx.x, NTILES);
    int wid = tile * 16 + g;
    int t = wid / N_NODES, n = wid - t * N_NODES;
    int deg = min(fill[n], CAP);
    int rs = n * CAP;
    int tb = t * N_NODES;
    int hsel = il >> 2;
    float adh = ALD0[(size_t)wid * 4 + hsel];
    for (int idx = il; idx < deg; idx += 16)
        srcs[idx][g] = csr_src[rs + idx];
    lds_fence();
    float ssum = 0.f, a0 = 0.f, a1 = 0.f, a2 = 0.f, a3 = 0.f;
    const bf16* hrow = XW0b + (size_t)tb * 64 + il * 4;
    const float* alsb = ALS0 + (size_t)tb * 4 + hsel;
    for (int k = 0; k < deg; k++) {
        int sx = srcs[k][g];
        float l = alsb[(size_t)sx * 4] + adh;
        l = l > 0.f ? l : 0.2f * l;
        float e = __expf(fminf(l, 80.f));
        ssum += e;
        ushort4 u = *(const ushort4*)(hrow + (size_t)sx * 64);
        a0 += e * bfu(u.x); a1 += e * bfu(u.y);
        a2 += e * bfu(u.z); a3 += e * bfu(u.w);
    }
    float iv = 1.f / (ssum + 1e-16f);
    float4 bv = *(const float4*)(b0 + il * 4);
    float v0 = a0 * iv + bv.x; v0 = v0 > 0.f ? v0 : (__expf(v0) - 1.f);
    float v1 = a1 * iv + bv.y; v1 = v1 > 0.f ? v1 : (__expf(v1) - 1.f);
    float v2 = a2 * iv + bv.z; v2 = v2 > 0.f ? v2 : (__expf(v2) - 1.f);
    float v3 = a3 * iv + bv.w; v3 = v3 > 0.f ? v3 : (__expf(v3) - 1.f);
    ushort4 o4;
    o4.x = f2bu(v0); o4.y = f2bu(v1); o4.z = f2bu(v2); o4.w = f2bu(v3);
    *(ushort4*)(H0b + (size_t)wid * 64 + il * 4) = o4;

    /* ---- fused layer-1 logits: ALS1/ALD1 from the f32 H0 registers ---- */
    float ps[4], pd[4];
#pragma unroll
    for (int h = 0; h < 4; h++) {
        float4 s4 = *(const float4*)(P1s + h * 64 + il * 4);
        float4 d4 = *(const float4*)(P1d + h * 64 + il * 4);
        ps[h] = v0 * s4.x + v1 * s4.y + v2 * s4.z + v3 * s4.w;
        pd[h] = v0 * d4.x + v1 * d4.y + v2 * d4.z + v3 * d4.w;
    }
#pragma unroll
    for (int o = 1; o <= 8; o <<= 1) {
#pragma unroll
        for (int h = 0; h < 4; h++) {
            ps[h] += __shfl_xor(ps[h], o, 64);
            pd[h] += __shfl_xor(pd[h], o, 64);
        }
    }
    if (il == 0) {
        float4 w1; w1.x = ps[0]; w1.y = ps[1]; w1.z = ps[2]; w1.w = ps[3];
        *(float4*)(ALS1 + (size_t)wid * 4) = w1;
        float4 w2; w2.x = pd[0]; w2.y = pd[1]; w2.z = pd[2]; w2.w = pd[3];
        *(float4*)(ALD1 + (size_t)wid * 4) = w2;
    }
}

/* -------- fused layer-1: TWO-PHASE exv-staged softmax+agg + GEMM + LN ---
   Phase 1: each exp computed ONCE per (edge,head) by the lane covering
   that edge, staged in exv (LDS); 16-lane shfl reduce for sums. Phase 2:
   per edge one broadcast exv float4 read + one distinct ushort4 row
   gather + 16 FMAs/lane. This is the round-6 structure (measured 48us,
   VALUBusy 37%) — single-pass variants regressed to 57-61us from
   lane-redundant transcendental work. deg>64 fallback: single-pass. */
__global__ __launch_bounds__(256) void k_fused1(const int* __restrict__ fill,
                                                const int* __restrict__ csr_src,
                                                const int* __restrict__ csr_eid,
                                                const bf16* __restrict__ H0b,
                                                const float* __restrict__ ALS1,
                                                const float* __restrict__ ALD1,
                                                const bf16* __restrict__ W1bt,
                                                const float* __restrict__ b1,
                                                const float* __restrict__ ln_g,
                                                const float* __restrict__ ln_b,
                                                bf16* __restrict__ HSb,
                                                float* __restrict__ out_alpha) {
    __shared__ __align__(16) union SM {
        struct { float exv[4][4][64][4]; unsigned short srcs[4][4][64]; } p;  /* 18 KB */
        struct { bf16 ast[16][264]; float ost[16][68]; } q;                   /* 12.8 KB */
    } sm;
    int tid = threadIdx.x;
    int wv = tid >> 6, lane = tid & 63;
    int sub = lane >> 4, il = lane & 15;
    int g = wv * 4 + sub;
    int tile = xcd_swizzle(blockIdx.x, NTILES);
    int wid = tile * 16 + g;
    int t = wid / N_NODES, n = wid - t * N_NODES;
    int deg = min(fill[n], CAP);
    int rs = n * CAP;
    int tb = t * N_NODES;
    bool do_out = (t == T_STEPS - 1);
    float4 ad4 = *(const float4*)(ALD1 + (size_t)wid * 4);
    float acc[4][4];
#pragma unroll
    for (int h = 0; h < 4; h++)
#pragma unroll
        for (int j = 0; j < 4; j++) acc[h][j] = 0.f;
    float iv0, iv1, iv2, iv3;
    const bf16* hrow = H0b + (size_t)tb * 64 + il * 4;
    const float* alsb = ALS1 + (size_t)tb * 4;

    /* wave-uniform softmax block count for the fast path */
    int mdf = (deg <= 64) ? deg : 0;
    mdf = max(mdf, __shfl_xor(mdf, 16, 64));
    mdf = max(mdf, __shfl_xor(mdf, 32, 64));
    int nbf = (mdf + 15) >> 4;

    if (deg <= 64) {
        /* phase 1: exp once per (edge, head); stage in exv */
        float s0 = 0.f, s1 = 0.f, s2 = 0.f, s3 = 0.f;
        for (int b = 0; b < nbf; b++) {
            int idxe = b * 16 + il;
            bool valid = idxe < deg;
            int src = csr_src[valid ? rs + idxe : rs];
            float4 as = *(const float4*)(alsb + (size_t)src * 4);
            float l0 = as.x + ad4.x; l0 = l0 > 0.f ? l0 : 0.2f * l0;
            float l1 = as.y + ad4.y; l1 = l1 > 0.f ? l1 : 0.2f * l1;
            float l2 = as.z + ad4.z; l2 = l2 > 0.f ? l2 : 0.2f * l2;
            float l3 = as.w + ad4.w; l3 = l3 > 0.f ? l3 : 0.2f * l3;
            float e0 = valid ? __expf(fminf(l0, 80.f)) : 0.f;
            float e1 = valid ? __expf(fminf(l1, 80.f)) : 0.f;
            float e2 = valid ? __expf(fminf(l2, 80.f)) : 0.f;
            float e3 = valid ? __expf(fminf(l3, 80.f)) : 0.f;
            s0 += e0; s1 += e1; s2 += e2; s3 += e3;
            float4 ex4; ex4.x = e0; ex4.y = e1; ex4.z = e2; ex4.w = e3;
            if (valid) {
                *(float4*)&sm.p.exv[wv][sub][idxe][0] = ex4;
                sm.p.srcs[wv][sub][idxe] = (unsigned short)src;
            }
        }
#pragma unroll
        for (int o = 1; o <= 8; o <<= 1) {
            s0 += __shfl_xor(s0, o, 64); s1 += __shfl_xor(s1, o, 64);
            s2 += __shfl_xor(s2, o, 64); s3 += __shfl_xor(s3, o, 64);
        }
        iv0 = 1.f / (s0 + 1e-16f); iv1 = 1.f / (s1 + 1e-16f);
        iv2 = 1.f / (s2 + 1e-16f); iv3 = 1.f / (s3 + 1e-16f);
        lds_fence();
        if (do_out) {
            for (int idxe = il; idxe < deg; idxe += 16) {
                float4 ex4 = *(const float4*)&sm.p.exv[wv][sub][idxe][0];
                float4 o4;
                o4.x = ex4.x * iv0; o4.y = ex4.y * iv1;
                o4.z = ex4.z * iv2; o4.w = ex4.w * iv3;
                int eid = csr_eid[rs + idxe];
                *(float4*)(out_alpha + (size_t)eid * 4) = o4;
            }
        }
        /* phase 2: aggregation — broadcast exv read + distinct row gather */
        for (int k = 0; k < deg; k++) {
            float4 ex = *(const float4*)&sm.p.exv[wv][sub][k][0];   /* broadcast */
            int sx = sm.p.srcs[wv][sub][k];
            ushort4 u = *(const ushort4*)(hrow + (size_t)sx * 64);  /* distinct 8B */
            float x0 = bfu(u.x), x1 = bfu(u.y), x2 = bfu(u.z), x3 = bfu(u.w);
            acc[0][0] += ex.x * x0; acc[0][1] += ex.x * x1; acc[0][2] += ex.x * x2; acc[0][3] += ex.x * x3;
            acc[1][0] += ex.y * x0; acc[1][1] += ex.y * x1; acc[1][2] += ex.y * x2; acc[1][3] += ex.y * x3;
            acc[2][0] += ex.z * x0; acc[2][1] += ex.z * x1; acc[2][2] += ex.z * x2; acc[2][3] += ex.z * x3;
            acc[3][0] += ex.w * x0; acc[3][1] += ex.w * x1; acc[3][2] += ex.w * x2; acc[3][3] += ex.w * x3;
        }
    } else {
        /* rare fallback (deg > 64): single-pass, lane-redundant exps */
        float s0 = 0.f, s1 = 0.f, s2 = 0.f, s3 = 0.f;
        for (int k = 0; k < deg; k++) {
            int sx = csr_src[rs + k];
            float4 as = *(const float4*)(alsb + (size_t)sx * 4);
            float l0 = as.x + ad4.x; l0 = l0 > 0.f ? l0 : 0.2f * l0;
            float l1 = as.y + ad4.y; l1 = l1 > 0.f ? l1 : 0.2f * l1;
            float l2 = as.z + ad4.z; l2 = l2 > 0.f ? l2 : 0.2f * l2;
            float l3 = as.w + ad4.w; l3 = l3 > 0.f ? l3 : 0.2f * l3;
            float e0 = __expf(fminf(l0, 80.f));
            float e1 = __expf(fminf(l1, 80.f));
            float e2 = __expf(fminf(l2, 80.f));
            float e3 = __expf(fminf(l3, 80.f));
            s0 += e0; s1 += e1; s2 += e2; s3 += e3;
            ushort4 u = *(const ushort4*)(hrow + (size_t)sx * 64);
            float x0 = bfu(u.x), x1 = bfu(u.y), x2 = bfu(u.z), x3 = bfu(u.w);
            acc[0][0] += e0 * x0; acc[0][1] += e0 * x1; acc[0][2] += e0 * x2; acc[0][3] += e0 * x3;
            acc[1][0] += e1 * x0; acc[1][1] += e1 * x1; acc[1][2] += e1 * x2; acc[1][3] += e1 * x3;
            acc[2][0] += e2 * x0; acc[2][1] += e2 * x1; acc[2][2] += e2 * x2; acc[2][3] += e2 * x3;
            acc[3][0] += e3 * x0; acc[3][1] += e3 * x1; acc[3][2] += e3 * x2; acc[3][3] += e3 * x3;
        }
        iv0 = 1.f / (s0 + 1e-16f); iv1 = 1.f / (s1 + 1e-16f);
        iv2 = 1.f / (s2 + 1e-16f); iv3 = 1.f / (s3 + 1e-16f);
        if (do_out) {
            for (int idxe = il; idxe < deg; idxe += 16) {
                int sx = csr_src[rs + idxe];
                float4 as = *(const float4*)(alsb + (size_t)sx * 4);
                float l0 = as.x + ad4.x; l0 = l0 > 0.f ? l0 : 0.2f * l0;
                float l1 = as.y + ad4.y; l1 = l1 > 0.f ? l1 : 0.2f * l1;
                float l2 = as.z + ad4.z; l2 = l2 > 0.f ? l2 : 0.2f * l2;
                float l3 = as.w + ad4.w; l3 = l3 > 0.f ? l3 : 0.2f * l3;
                float4 o4;
                o4.x = __expf(fminf(l0, 80.f)) * iv0;
                o4.y = __expf(fminf(l1, 80.f)) * iv1;
                o4.z = __expf(fminf(l2, 80.f)) * iv2;
                o4.w = __expf(fminf(l3, 80.f)) * iv3;
                int eid = csr_eid[rs + idxe];
                *(float4*)(out_alpha + (size_t)eid * 4) = o4;
            }
        }
    }

    /* ---- phase 3: stage agg (bf16) -> 16x64x256 MFMA -> LN -> HSb ---- */
    __syncthreads();                       /* all exv/srcs reads complete */
    float ivh[4] = { iv0, iv1, iv2, iv3 };
#pragma unroll
    for (int h = 0; h < 4; h++) {
        ushort4 o4;
        o4.x = f2bu(acc[h][0] * ivh[h]);
        o4.y = f2bu(acc[h][1] * ivh[h]);
        o4.z = f2bu(acc[h][2] * ivh[h]);
        o4.w = f2bu(acc[h][3] * ivh[h]);
        *(ushort4*)&sm.q.ast[g][h * 64 + il * 4] = o4;   /* K = h*64 + feature */
    }
    __syncthreads();
    /* wave wv computes output columns [wv*16, wv*16+16) */
    int m = il, quad = sub;
    floatx4 ga = {0.f, 0.f, 0.f, 0.f};
    const bf16* wrow = W1bt + (size_t)(wv * 16 + m) * 256 + quad * 8;
#pragma unroll
    for (int kb = 0; kb < 8; kb++) {
        short8 afk = *(const short8*)&sm.q.ast[m][kb * 32 + quad * 8];
        short8 bfk = *(const short8*)(wrow + kb * 32);
        ga = __builtin_amdgcn_mfma_f32_16x16x32_bf16(afk, bfk, ga, 0, 0, 0);
    }
#pragma unroll
    for (int r = 0; r < 4; r++)
        sm.q.ost[quad * 4 + r][wv * 16 + m] = ga[r];
    __syncthreads();
    /* LN: wave wv handles rows wv*4+quad; 16 lanes (m) cover 64 cols */
    int row = wv * 4 + quad;
    float4 vv = *(const float4*)&sm.q.ost[row][m * 4];
    float4 bb = *(const float4*)(b1 + m * 4);
    float v0 = vv.x * 0.25f + bb.x; v0 = v0 > 0.f ? v0 : (__expf(v0) - 1.f);
    float v1 = vv.y * 0.25f + bb.y; v1 = v1 > 0.f ? v1 : (__expf(v1) - 1.f);
    float v2 = vv.z * 0.25f + bb.z; v2 = v2 > 0.f ? v2 : (__expf(v2) - 1.f);
    float v3 = vv.w * 0.25f + bb.w; v3 = v3 > 0.f ? v3 : (__expf(v3) - 1.f);
    float sv = v0 + v1 + v2 + v3;
#pragma unroll
    for (int o = 1; o <= 8; o <<= 1) sv += __shfl_xor(sv, o, 64);
    float mu = sv * (1.f / 64.f);
    float d0 = v0 - mu, d1 = v1 - mu, d2 = v2 - mu, d3 = v3 - mu;
    float qv = d0 * d0 + d1 * d1 + d2 * d2 + d3 * d3;
#pragma unroll
    for (int o = 1; o <= 8; o <<= 1) qv += __shfl_xor(qv, o, 64);
    float rinv = rsqrtf(qv * (1.f / 64.f) + 1e-5f);
    float4 gg = *(const float4*)(ln_g + m * 4);
    float4 lb = *(const float4*)(ln_b + m * 4);
    ushort4 ho;
    ho.x = f2bu(d0 * rinv * gg.x + lb.x);
    ho.y = f2bu(d1 * rinv * gg.y + lb.y);
    ho.z = f2bu(d2 * rinv * gg.z + lb.z);
    ho.w = f2bu(d3 * rinv * gg.w + lb.w);
    *(ushort4*)(HSb + (size_t)(tile * 16 + row) * 64 + m * 4) = ho;
}

/* ---------------- GRU: 625 blocks, 4 waves split the 192 gate rows -------
   One block per 16-node tile; wave wv owns h-features [wv*16, wv*16+16).
   B-fragments (bf16 W_ih/W_hh rows) live in registers across all 6 steps;
   h is exchanged via a padded LDS tile with 2 barriers/step. h0 = 0. */
__global__ __launch_bounds__(256) void k_gru(const bf16* __restrict__ HSb,
                                             const bf16* __restrict__ wihb,
                                             const float* __restrict__ b_ih,
                                             const bf16* __restrict__ whhb,
                                             const float* __restrict__ b_hh,
                                             float* __restrict__ outh) {
    __shared__ __align__(16) bf16 hbuf[16 * 72];   /* 2.25 KB, stride-72 pad */
    int tid = threadIdx.x;
    int wv = tid >> 6, lane = tid & 63;
    int rb = blockIdx.x * 16;
    int m = lane & 15, quad = lane >> 4;
    int fb = wv * 16;
    const int rowR = (fb + m) * 64, rowZ = (64 + fb + m) * 64, rowG = (128 + fb + m) * 64;
    short8 Br0 = *(const short8*)(wihb + rowR + quad * 8);
    short8 Br1 = *(const short8*)(wihb + rowR + 32 + quad * 8);
    short8 Bz0 = *(const short8*)(wihb + rowZ + quad * 8);
    short8 Bz1 = *(const short8*)(wihb + rowZ + 32 + quad * 8);
    short8 Bg0 = *(const short8*)(wihb + rowG + quad * 8);
    short8 Bg1 = *(const short8*)(wihb + rowG + 32 + quad * 8);
    short8 Cr0 = *(const short8*)(whhb + rowR + quad * 8);
    short8 Cr1 = *(const short8*)(whhb + rowR + 32 + quad * 8);
    short8 Cz0 = *(const short8*)(whhb + rowZ + quad * 8);
    short8 Cz1 = *(const short8*)(whhb + rowZ + 32 + quad * 8);
    short8 Cg0 = *(const short8*)(whhb + rowG + quad * 8);
    short8 Cg1 = *(const short8*)(whhb + rowG + 32 + quad * 8);
    float biR = b_ih[fb + m], biZ = b_ih[64 + fb + m], biG = b_ih[128 + fb + m];
    float bhR = b_hh[fb + m], bhZ = b_hh[64 + fb + m], bhG = b_hh[128 + fb + m];
    float hprev[4] = {0.f, 0.f, 0.f, 0.f};

    for (int t = 0; t < T_STEPS; t++) {
        const bf16* xr = HSb + ((size_t)t * N_NODES + rb + m) * 64;
        short8 ax0 = *(const short8*)(xr + quad * 8);
        short8 ax1 = *(const short8*)(xr + 32 + quad * 8);
        short8 ah0, ah1;
        if (t > 0) {
            ah0 = *(const short8*)(hbuf + m * 72 + quad * 8);
            ah1 = *(const short8*)(hbuf + m * 72 + 32 + quad * 8);
        }
        __syncthreads();   /* all reads of old h done before anyone writes new h */
        floatx4 aR = {0.f, 0.f, 0.f, 0.f}, aZ = {0.f, 0.f, 0.f, 0.f};
        floatx4 aGi = {0.f, 0.f, 0.f, 0.f}, aGh = {0.f, 0.f, 0.f, 0.f};
        aR = __builtin_amdgcn_mfma_f32_16x16x32_bf16(ax0, Br0, aR, 0, 0, 0);
        aR = __builtin_amdgcn_mfma_f32_16x16x32_bf16(ax1, Br1, aR, 0, 0, 0);
        aZ = __builtin_amdgcn_mfma_f32_16x16x32_bf16(ax0, Bz0, aZ, 0, 0, 0);
        aZ = __builtin_amdgcn_mfma_f32_16x16x32_bf16(ax1, Bz1, aZ, 0, 0, 0);
        aGi = __builtin_amdgcn_mfma_f32_16x16x32_bf16(ax0, Bg0, aGi, 0, 0, 0);
        aGi = __builtin_amdgcn_mfma_f32_16x16x32_bf16(ax1, Bg1, aGi, 0, 0, 0);
        if (t > 0) {
            aR = __builtin_amdgcn_mfma_f32_16x16x32_bf16(ah0, Cr0, aR, 0, 0, 0);
            aR = __builtin_amdgcn_mfma_f32_16x16x32_bf16(ah1, Cr1, aR, 0, 0, 0);
            aZ = __builtin_amdgcn_mfma_f32_16x16x32_bf16(ah0, Cz0, aZ, 0, 0, 0);
            aZ = __builtin_amdgcn_mfma_f32_16x16x32_bf16(ah1, Cz1, aZ, 0, 0, 0);
            aGh = __builtin_amdgcn_mfma_f32_16x16x32_bf16(ah0, Cg0, aGh, 0, 0, 0);
            aGh = __builtin_amdgcn_mfma_f32_16x16x32_bf16(ah1, Cg1, aGh, 0, 0, 0);
        }
#pragma unroll
        for (int r = 0; r < 4; r++) {
            float rr = 1.f / (1.f + __expf(-(aR[r] + biR + bhR)));
            float z  = 1.f / (1.f + __expf(-(aZ[r] + biZ + bhZ)));
            float g  = tanhf(aGi[r] + biG + rr * (aGh[r] + bhG));
            hprev[r] = (1.f - z) * g + z * hprev[r];
        }
        if (t < T_STEPS - 1) {
#pragma unroll
            for (int r = 0; r < 4; r++)
                hbuf[(quad * 4 + r) * 72 + fb + m] = __float2bfloat16(hprev[r]);
            __syncthreads();   /* writes visible before next step's reads */
        }
    }
#pragma unroll
    for (int r = 0; r < 4; r++)
        outh[(size_t)(rb + quad * 4 + r) * 64 + fb + m] = hprev[r];
}

/* ---------------- launch ---------------- */

extern "C" void kernel_launch(void* const* d_in, const int* in_sizes, int n_in,
                              void* d_out, int out_size, void* d_ws, size_t ws_size,
                              hipStream_t stream) {
    const float* x      = (const float*)d_in[0];
    const int*   ei     = (const int*)d_in[1];
    const float* W0     = (const float*)d_in[2];
    const float* a_src0 = (const float*)d_in[3];
    const float* a_dst0 = (const float*)d_in[4];
    const float* b0     = (const float*)d_in[5];
    const float* W1     = (const float*)d_in[6];
    const float* a_src1 = (const float*)d_in[7];
    const float* a_dst1 = (const float*)d_in[8];
    const float* b1     = (const float*)d_in[9];
    const float* ln_g   = (const float*)d_in[10];
    const float* ln_b   = (const float*)d_in[11];
    const float* W_ih   = (const float*)d_in[12];
    const float* W_hh   = (const float*)d_in[13];
    const float* b_ih   = (const float*)d_in[14];
    const float* b_hh   = (const float*)d_in[15];
    float* out = (float*)d_out;

    char* w = (char*)d_ws;
    size_t off = 0;
    auto take = [&](size_t bytes) -> void* {
        void* p = w + off;
        off = (off + bytes + 255) & ~(size_t)255;
        return p;
    };
    int*   fill    = (int*)take(N_NODES * 4);
    int*   csr_src = (int*)take((size_t)N_NODES * CAP * 4);
    int*   csr_eid = (int*)take((size_t)N_NODES * CAP * 4);
    bf16*  XW0b    = (bf16*)take((size_t)TN * 64 * 2);
    float* ALS0    = (float*)take((size_t)TN * 4 * 4);
    float* ALD0    = (float*)take((size_t)TN * 4 * 4);
    bf16*  H0b     = (bf16*)take((size_t)TN * 64 * 2);
    float* P0s     = (float*)take(256 * 4);
    float* P0d     = (float*)take(256 * 4);
    float* P1s     = (float*)take(256 * 4);
    float* P1d     = (float*)take(256 * 4);
    float* ALS1    = (float*)take((size_t)TN * 4 * 4);
    float* ALD1    = (float*)take((size_t)TN * 4 * 4);
    bf16*  HSb     = (bf16*)take((size_t)TN * 64 * 2);
    bf16*  W0bt    = (bf16*)take(4096 * 2);
    bf16*  W1bt    = (bf16*)take(16384 * 2);
    bf16*  wihb    = (bf16*)take(12288 * 2);
    bf16*  whhb    = (bf16*)take(12288 * 2);
    (void)ws_size; (void)in_sizes; (void)n_in; (void)out_size;

    const int B = 256;
    float* out_ei = out + (size_t)N_NODES * HID + (size_t)EP * HEADS;

    /* CSR build (direct fixed-stride buckets) + prep */
    hipMemsetAsync(fill, 0, N_NODES * 4, stream);
    k_prep<<<178, B, 0, stream>>>(W0, W1, a_src0, a_dst0, a_src1, a_dst1, W_ih, W_hh,
                                  W0bt, W1bt, wihb, whhb, P0s, P0d, P1s, P1d);
    k_scatter<<<(EP + B - 1) / B, B, 0, stream>>>(ei, fill, csr_src, csr_eid, out_ei);

    const int GT = (NTILES + 3) / 4;   /* 938 blocks for 16-row-tile MFMA kernels */
    /* GAT layer 0 (+ layer-1 logits fused into the epilogue) */
    k_gemm0<<<GT, B, 0, stream>>>(x, W0bt, P0s, P0d, XW0b, ALS0, ALD0);
    k_fused0<<<NTILES, B, 0, stream>>>(fill, csr_src, XW0b, ALS0, ALD0, b0,
                                       P1s, P1d, H0b, ALS1, ALD1);

    /* GAT layer 1 (+ epilogue GEMM + LN fused) */
    k_fused1<<<NTILES, B, 0, stream>>>(fill, csr_src, csr_eid, H0b, ALS1, ALD1,
                                       W1bt, b1, ln_g, ln_b, HSb,
                                       out + (size_t)N_NODES * HID);

    /* GRU: all 6 steps, 625 blocks × 4 gate-split waves, writes hT to out */
    k_gru<<<N_NODES / 16, B, 0, stream>>>(HSb, wihb, b_ih, whhb, b_hh, out);
}